// Round 5
// baseline (762.013 us; speedup 1.0000x reference)
//
#include <hip/hip_runtime.h>

typedef _Float16 half_t;
typedef __attribute__((ext_vector_type(8))) _Float16 half8;
typedef __attribute__((ext_vector_type(4))) _Float16 half4v;
typedef __attribute__((ext_vector_type(4))) float f32x4;

#define MFMA16(a,b,c) __builtin_amdgcn_mfma_f32_16x16x32_f16((a),(b),(c),0,0,0)

__device__ __forceinline__ void gld_lds16(const half_t* g, half_t* l){
    __builtin_amdgcn_global_load_lds((__attribute__((address_space(1))) void*)(g),
                                     (__attribute__((address_space(3))) void*)(l), 16, 0, 0);
}

// ---------------- fp32 -> fp16 convert: x and the 4 weight matrices, one dispatch ----------------
__global__ __launch_bounds__(256) void cvt_all(const float* __restrict__ x,
                                               const float* __restrict__ w0, const float* __restrict__ w1,
                                               const float* __restrict__ w2, const float* __restrict__ w3,
                                               half_t* __restrict__ xh, half_t* __restrict__ w4){
    int b = blockIdx.x;
    if (b < 16384){
        int i = b * 256 + threadIdx.x;
        float4 v = ((const float4*)x)[i];
        half4v h = { (half_t)v.x, (half_t)v.y, (half_t)v.z, (half_t)v.w };
        ((half4v*)xh)[i] = h;
    } else {
        int wi   = b - 16384;
        int widx = wi >> 12;                    // 4096 blocks per weight
        int i    = (wi & 4095) * 256 + threadIdx.x;
        const float* srcs[4] = {w0, w1, w2, w3};
        float4 v = ((const float4*)srcs[widx])[i];
        half4v h = { (half_t)v.x, (half_t)v.y, (half_t)v.z, (half_t)v.w };
        ((half4v*)w4)[(size_t)widx * 1048576 + i] = h;
    }
}

// ---------------- 256x256x64 8-phase NT GEMM (T2+T3+T4+T5) ---------------- (frozen from R2)
#define VMWAIT_(n) asm volatile("s_waitcnt vmcnt(" #n ")" ::: "memory")
#define VMWAIT(n)  VMWAIT_(n)

#define STAGE8(hh) { \
    const int Tt2 = (hh) >> 2, jj2 = (hh) & 3; \
    half_t* db = smem + ((jj2 & 1) << 15) + ((Tt2 & 1) << 14) + ((jj2 >> 1) << 13); \
    const half_t* Gs = ((jj2 & 1) ? Bg : Ag) + Tt2*64 + ((jj2 >> 1) << 5); \
    gld_lds16(Gs + off0, db + d0); \
    gld_lds16(Gs + off1, db + d1); \
}

#define PHASE8(Tt, jj, hh, VMN) { \
    half_t* Ah = smem + (((Tt) & 1) << 14) + (((jj) >> 1) << 13); \
    half_t* Bh = Ah + 32768; \
    half8 af[4], bf[4]; \
    _Pragma("unroll") for (int x = 0; x < 4; x++) af[x] = *(const half8*)(Ah + (((jj)&1)*4 + x)*1024 + cA); \
    _Pragma("unroll") for (int y = 0; y < 4; y++) bf[y] = *(const half8*)(Bh + y*1024 + cB); \
    if ((hh) < 128) STAGE8(hh); \
    if ((jj) & 1) VMWAIT(VMN); \
    asm volatile("s_barrier" ::: "memory"); \
    __builtin_amdgcn_s_setprio(1); \
    _Pragma("unroll") for (int x = 0; x < 4; x++) \
      _Pragma("unroll") for (int y = 0; y < 4; y++) \
        acc[((jj)&1)*4 + x][y] = MFMA16(af[x], bf[y], acc[((jj)&1)*4 + x][y]); \
    __builtin_amdgcn_s_setprio(0); \
    __builtin_amdgcn_sched_barrier(0); \
    asm volatile("s_barrier" ::: "memory"); \
}

__global__ __launch_bounds__(512) void gemm8(const half_t* __restrict__ A, const half_t* __restrict__ B,
                                             half_t* __restrict__ Qw, half_t* __restrict__ Kw,
                                             half_t* __restrict__ Vt, float* __restrict__ Co, int kind){
    const int tid  = threadIdx.x;
    const int lane = tid & 63;
    const int w4   = lane >> 4;
    const int l15  = lane & 15;
    const int l7   = lane & 7;
    const int wav  = tid >> 6;
    const int wavM = wav >> 2;      // 0..1  (M half)
    const int wnq  = wav & 3;       // 0..3  (N quarter)

    const int nwg = gridDim.x;
    const int wg  = blockIdx.x;
    const int swz = (wg & 7) * (nwg >> 3) + (wg >> 3);
    const int bm  = swz & 31;       // M/256 = 32
    const int bn  = swz >> 5;

    __shared__ __align__(16) half_t smem[65536];   // 128 KiB

    const half_t* Ag = A + (size_t)bm * 256 * 2048;
    const half_t* Bg = B + (size_t)bn * 256 * 2048;

    const int p0  = tid >> 3, q0 = tid & 7, c0 = q0 ^ (p0 & 7);
    const int off0 = (p0 + ((c0 >> 2) << 7)) * 2048 + ((c0 & 3) << 3);
    const int off1 = off0 + 131072;                 // +64 rows * 2048
    const int d0  = tid * 8, d1 = d0 + 4096;

    const int cA = l15*64 + (((w4 | (wavM << 2)) ^ l7) << 3);
    const int cB = ((wnq & 1)*64 + l15)*64 + (((w4 | ((wnq >> 1) << 2)) ^ l7) << 3);

    f32x4 acc[8][4] = {};

#pragma unroll
    for (int h = 0; h < 6; h++) STAGE8(h);
    VMWAIT(4);
    asm volatile("s_barrier" ::: "memory");

    for (int it = 0; it < 15; it++){
        const int h0 = it*8 + 6;
        PHASE8(2*it,   0, h0,     6); PHASE8(2*it,   1, h0 + 1, 6);
        PHASE8(2*it,   2, h0 + 2, 6); PHASE8(2*it,   3, h0 + 3, 6);
        PHASE8(2*it+1, 0, h0 + 4, 6); PHASE8(2*it+1, 1, h0 + 5, 6);
        PHASE8(2*it+1, 2, h0 + 6, 6); PHASE8(2*it+1, 3, h0 + 7, 6);
    }
    PHASE8(30, 0, 126, 6); PHASE8(30, 1, 127, 6);
    PHASE8(30, 2, 128, 6); PHASE8(30, 3, 129, 2);
    PHASE8(31, 0, 130, 0); PHASE8(31, 1, 131, 0);
    PHASE8(31, 2, 132, 0); PHASE8(31, 3, 133, 0);

    const int mB = bm*256 + wavM*128 + w4*4;
    const int nB = bn*256 + wnq*64 + l15;

    if (kind == 0){
#pragma unroll
        for (int mi = 0; mi < 8; mi++)
#pragma unroll
            for (int ni = 0; ni < 4; ni++){
                int n  = nB + ni*16;
                int which = n >> 11;
                int nb = n & 2047;
                int m0 = mB + mi*16;
                if (which < 2){
                    half_t* dst = which ? Kw : Qw;
#pragma unroll
                    for (int r = 0; r < 4; r++){
                        int m = m0 + r;
                        dst[(((size_t)(m >> 11)*16 + (nb >> 7))*2048 + (m & 2047))*128 + (nb & 127)] = (half_t)acc[mi][ni][r];
                    }
                } else {
                    half4v hv = {(half_t)acc[mi][ni][0], (half_t)acc[mi][ni][1],
                                 (half_t)acc[mi][ni][2], (half_t)acc[mi][ni][3]};
                    *(half4v*)(Vt + (((size_t)(m0 >> 11)*16 + (nb >> 7))*128 + (nb & 127))*2048 + (m0 & 2047)) = hv;
                }
            }
    } else {
#pragma unroll
        for (int mi = 0; mi < 8; mi++)
#pragma unroll
            for (int ni = 0; ni < 4; ni++){
                int n  = nB + ni*16;
                int m0 = mB + mi*16;
#pragma unroll
                for (int r = 0; r < 4; r++)
                    Co[(size_t)(m0 + r)*2048 + n] = acc[mi][ni][r];
            }
    }
}

// ---------------- RoPE in-place on Q/K, vectorized: 8 (d,d+64) pairs per thread ----------------
__global__ __launch_bounds__(256) void rope_k(half_t* __restrict__ Qw, half_t* __restrict__ Kw,
                                              const float* __restrict__ cs, const float* __restrict__ sn){
    int t  = blockIdx.x * 256 + threadIdx.x;   // 1,048,576 threads
    int c8 = t & 7;                            // 8-wide d chunk
    int s  = (t >> 3) & 2047;
    int bh = t >> 14;
    size_t base = ((size_t)bh*2048 + s)*128 + c8*8;
    const float4* cp = (const float4*)(cs + s*64 + c8*8);
    const float4* sp = (const float4*)(sn + s*64 + c8*8);
    float4 c0 = cp[0], c1 = cp[1];
    float4 s0 = sp[0], s1 = sp[1];
    float c[8]  = {c0.x,c0.y,c0.z,c0.w,c1.x,c1.y,c1.z,c1.w};
    float si[8] = {s0.x,s0.y,s0.z,s0.w,s1.x,s1.y,s1.z,s1.w};

    half8 qlo = *(const half8*)(Qw + base), qhi = *(const half8*)(Qw + base + 64);
    half8 klo = *(const half8*)(Kw + base), khi = *(const half8*)(Kw + base + 64);
    half8 qlo_o, qhi_o, klo_o, khi_o;
#pragma unroll
    for (int j = 0; j < 8; j++){
        float q1 = (float)qlo[j], q2 = (float)qhi[j];
        qlo_o[j] = (half_t)(q1*c[j] - q2*si[j]);
        qhi_o[j] = (half_t)(q1*si[j] + q2*c[j]);
        float k1 = (float)klo[j], k2 = (float)khi[j];
        klo_o[j] = (half_t)(k1*c[j] - k2*si[j]);
        khi_o[j] = (half_t)(k1*si[j] + k2*c[j]);
    }
    *(half8*)(Qw + base)      = qlo_o;
    *(half8*)(Qw + base + 64) = qhi_o;
    *(half8*)(Kw + base)      = klo_o;
    *(half8*)(Kw + base + 64) = khi_o;
}

// ---------------- Flash attention: KVBLK=32, 4 blocks/CU, dbuf + counted vmcnt ----------------
// Q[bh][s][128], K[bh][s][128], Vt[bh][128][s] -> AO [b*2048+s][h*128+d]
// R4 showed ~47% issue-idle at 2 blocks/CU: softmax serial chains (shfl/exp2/P-roundtrip)
// exposed with only 2 waves/SIMD. KVBLK=32 shrinks LDS to 40KB -> 4 blocks/CU = 4 waves/SIMD,
// halves per-iter serial chains; same total math. Staging stays global_load_lds + vmcnt(4).
// LDS: K dbuf 2x8K | V dbuf 2x8K | Ps 4x2K = 40KB.
__global__ __launch_bounds__(256, 4) void attn_k(const half_t* __restrict__ Q, const half_t* __restrict__ K,
                                                 const half_t* __restrict__ Vt, half_t* __restrict__ AO){
    const int tid  = threadIdx.x;
    const int lane = tid & 63;
    const int w    = lane >> 4;
    const int l15  = lane & 15;
    const int l7   = lane & 7;
    const int l3   = lane & 3;
    const int wav  = tid >> 6;
    const int bid  = blockIdx.x;          // 1024
    const int qt   = (bid >> 3) & 15;     // 16 q-tiles of 128
    const int bh   = (bid & 7) * 8 + (bid >> 7);   // 8 heads per XCD group

    __shared__ __align__(16) half_t smem[20480];   // 40 KiB
    // [0,8192): K dbuf (2x4096); [8192,16384): V dbuf (2x4096); [16384,20480): Ps (wav*1024)
    half_t* Ps = smem + 16384 + wav*1024;
    half_t* Ob = smem + wav*4096;          // epilogue overlay on K/V dbuf (16K halves)

    const float SSC = 0.08838834764831845f * 1.4426950408889634f;  // 1/sqrt(128) * log2(e)

    const half_t* Qb = Q + ((size_t)bh*2048 + qt*128 + wav*32)*128;
    half8 aq[2][4];
#pragma unroll
    for (int qi = 0; qi < 2; qi++)
#pragma unroll
        for (int ks = 0; ks < 4; ks++){
            half8 t = *(const half8*)(Qb + (qi*16 + l15)*128 + ks*32 + w*8);
            aq[qi][ks] = t * (half_t)SSC;       // fold softmax scale into Q
        }

    const half_t* Kbase = K  + (size_t)bh*2048*128;
    const half_t* Vbase = Vt + (size_t)bh*128*2048;

    // staging offsets: K: c=tid+i*256 (i<2): key=c>>4 (0..31), 16B chunk pc=c&15, XOR key&7
    //                  V: d=c>>2 (0..127), 16B chunk pv=c&3 of 32-s row, XOR d&3
    // prologue: tile 0 into buffer 0
#pragma unroll
    for (int i = 0; i < 2; i++){
        int c = tid + i*256;
        int key = c >> 4, pc = c & 15;
        gld_lds16(Kbase + key*128 + ((pc ^ (key & 7)) << 3), smem + c*8);
    }
#pragma unroll
    for (int i = 0; i < 2; i++){
        int c = tid + i*256;
        int d = c >> 2, pv = c & 3;
        gld_lds16(Vbase + (size_t)d*2048 + ((pv ^ (d & 3)) << 3), smem + 8192 + c*8);
    }

    f32x4 oacc[8][2] = {};
    float m_[2] = {-1e30f, -1e30f};
    float l_[2] = {0.0f, 0.0f};

    for (int kt = 0; kt < 64; kt++){
        half_t* kb = smem + ((kt & 1) << 12);
        half_t* vb = smem + 8192 + ((kt & 1) << 12);

        if (kt < 63){
            const half_t* Kb = Kbase + (size_t)(kt + 1)*4096;
            const half_t* Vb = Vbase + (kt + 1)*32;
            half_t* kn = smem + (((kt + 1) & 1) << 12);
            half_t* vn = smem + 8192 + (((kt + 1) & 1) << 12);
#pragma unroll
            for (int i = 0; i < 2; i++){
                int c = tid + i*256;
                int key = c >> 4, pc = c & 15;
                gld_lds16(Kb + key*128 + ((pc ^ (key & 7)) << 3), kn + c*8);
            }
#pragma unroll
            for (int i = 0; i < 2; i++){
                int c = tid + i*256;
                int d = c >> 2, pv = c & 3;
                gld_lds16(Vb + (size_t)d*2048 + ((pv ^ (d & 3)) << 3), vn + c*8);
            }
            VMWAIT(4);      // tile kt resident (its 4 loads are the oldest)
        } else {
            VMWAIT(0);      // last tile: drain
        }
        asm volatile("s_barrier" ::: "memory");

        // S^T = K @ Q^T : rows=key (2 tiles of 16), cols=q (2 tiles)
        f32x4 sacc[2][2] = {};
#pragma unroll
        for (int ks = 0; ks < 4; ks++){
#pragma unroll
            for (int t = 0; t < 2; t++){
                half8 kf = *(const half8*)(kb + (t*16 + l15)*128 + (((ks*4 + w) ^ l7) << 3));
                sacc[t][0] = MFMA16(kf, aq[0][ks], sacc[t][0]);
                sacc[t][1] = MFMA16(kf, aq[1][ks], sacc[t][1]);
            }
        }

        // online softmax per q-column (scaled domain); defer-max rescale (exact)
#pragma unroll
        for (int qi = 0; qi < 2; qi++){
            float mx = sacc[0][qi][0];
#pragma unroll
            for (int t = 0; t < 2; t++)
#pragma unroll
                for (int r = 0; r < 4; r++) mx = fmaxf(mx, sacc[t][qi][r]);
            mx = fmaxf(mx, __shfl_xor(mx, 16));
            mx = fmaxf(mx, __shfl_xor(mx, 32));
            unsigned long long upd = __ballot(mx > m_[qi]);
            if (upd){
                float mn    = fmaxf(m_[qi], mx);
                float alpha = exp2f(m_[qi] - mn);
                m_[qi] = mn;
                l_[qi] *= alpha;
#pragma unroll
                for (int t = 0; t < 8; t++)
#pragma unroll
                    for (int r = 0; r < 4; r++) oacc[t][qi][r] *= alpha;
            }
            float mq = m_[qi];
            float sum = 0.0f;
#pragma unroll
            for (int t = 0; t < 2; t++){
                float p0 = exp2f(sacc[t][qi][0] - mq);
                float p1 = exp2f(sacc[t][qi][1] - mq);
                float p2 = exp2f(sacc[t][qi][2] - mq);
                float p3 = exp2f(sacc[t][qi][3] - mq);
                sum += (p0 + p1) + (p2 + p3);
                half4v hv = {(half_t)p0, (half_t)p1, (half_t)p2, (half_t)p3};
                // row = qi*16+l15 (32 halves); 16B chunk = t*2+(w>>1), XOR row&3 (= l15&3)
                *(half4v*)(Ps + (qi*16 + l15)*32 + (((t*2 + (w >> 1)) ^ l3) << 3) + (w & 1)*4) = hv;
            }
            sum += __shfl_xor(sum, 16);
            sum += __shfl_xor(sum, 32);
            l_[qi] += sum;
        }

        // O^T += V^T @ P^T  (single K=32 step)
        {
            half8 pf0 = *(const half8*)(Ps + l15*32        + ((w ^ l3) << 3));
            half8 pf1 = *(const half8*)(Ps + (16 + l15)*32 + ((w ^ l3) << 3));
#pragma unroll
            for (int t = 0; t < 8; t++){
                half8 vf = *(const half8*)(vb + (t*16 + l15)*32 + ((w ^ l3) << 3));
                oacc[t][0] = MFMA16(vf, pf0, oacc[t][0]);
                oacc[t][1] = MFMA16(vf, pf1, oacc[t][1]);
            }
        }

        asm volatile("s_barrier" ::: "memory");   // frees kb/vb for restage at kt+2
    }

    // epilogue: transpose O^T -> O through LDS, coalesced global stores
    float inv[2] = {1.0f / l_[0], 1.0f / l_[1]};
#pragma unroll
    for (int t = 0; t < 8; t++)
#pragma unroll
        for (int qi = 0; qi < 2; qi++){
            int q  = qi*16 + l15;
            int c8 = t*2 + (w>>1);
            int pc = c8 ^ l7;
            half4v hv = {(half_t)(oacc[t][qi][0]*inv[qi]), (half_t)(oacc[t][qi][1]*inv[qi]),
                         (half_t)(oacc[t][qi][2]*inv[qi]), (half_t)(oacc[t][qi][3]*inv[qi])};
            *(half4v*)(Ob + q*128 + pc*8 + (w&1)*4) = hv;
        }
    const int b = bh >> 4, h = bh & 15;
#pragma unroll
    for (int it = 0; it < 8; it++){
        int q  = it*4 + w;
        half8 rd = *(const half8*)(Ob + q*128 + ((l15 ^ (q&7)) << 3));
        int s = qt*128 + wav*32 + q;
        *(half8*)(AO + ((size_t)(b*2048 + s))*2048 + h*128 + l15*8) = rd;
    }
}

extern "C" void kernel_launch(void* const* d_in, const int* in_sizes, int n_in,
                              void* d_out, int out_size, void* d_ws, size_t ws_size,
                              hipStream_t stream){
    const float* x  = (const float*)d_in[0];
    const float* cs = (const float*)d_in[1];
    const float* sn = (const float*)d_in[2];
    const float* Wq = (const float*)d_in[3];
    const float* Wk = (const float*)d_in[4];
    const float* Wv = (const float*)d_in[5];
    const float* Wo = (const float*)d_in[6];

    half_t* ws = (half_t*)d_ws;
    half_t* xh = ws;
    half_t* w4 = ws + (size_t)16777216;
    half_t* qw = ws + (size_t)33554432;
    half_t* kw = ws + (size_t)50331648;
    half_t* vt = ws + (size_t)67108864;
    half_t* ao = ws + (size_t)83886080;

    cvt_all<<<32768, 256, 0, stream>>>(x, Wq, Wk, Wv, Wo, xh, w4);

    gemm8<<<768, 512, 0, stream>>>(xh, w4, qw, kw, vt, nullptr, 0);
    rope_k<<<4096, 256, 0, stream>>>(qw, kw, cs, sn);
    attn_k<<<1024, 256, 0, stream>>>(qw, kw, vt, ao);
    gemm8<<<256, 512, 0, stream>>>(ao, w4 + 12582912, nullptr, nullptr, nullptr,
                                   (float*)d_out, 1);
}